// Round 5
// baseline (364.792 us; speedup 1.0000x reference)
//
#include <hip/hip_runtime.h>

#define N_DST 25000
#define E_NUM 400000

typedef __bf16 bf16x8 __attribute__((ext_vector_type(8)));
typedef __bf16 bf16x4 __attribute__((ext_vector_type(4)));
typedef __bf16 bf16x2 __attribute__((ext_vector_type(2)));
typedef float  f32x4  __attribute__((ext_vector_type(4)));

__device__ __forceinline__ float fast_cos(float x) {
  float r = x * 0.15915494309189535f;
  r = r - floorf(r);
  return __builtin_amdgcn_cosf(r);
}

__device__ __forceinline__ void gload_lds16(const void* g, void* l) {
  __builtin_amdgcn_global_load_lds(
      (const __attribute__((address_space(1))) unsigned int*)g,
      (__attribute__((address_space(3))) unsigned int*)l, 16, 0, 0);
}

// pack W into frag-contiguous bf16: out[fid*64+lane] = W[n][g*8..g*8+7]
// fid = (ks*4 + w)*NFRAGW + nf; n = w*(NC/4)+nf*16+(lane&15); g = ks*4+(lane>>4)
__device__ __forceinline__ void pack_frag(const float* __restrict__ W0,
    const float* __restrict__ W1, int stride, int NC, int idx, __bf16* __restrict__ out) {
  int lane = idx & 63, fid = idx >> 6;
  int nfw = NC >> 6;
  int perks = nfw << 2;
  int ks = fid / perks, rem = fid - ks * perks;
  int w = rem / nfw, nf = rem - w * nfw;
  int n = w * (NC >> 2) + nf * 16 + (lane & 15);
  int g = (ks << 2) + (lane >> 4);
  const float* src = (W1 && n >= 128) ? (W1 + (size_t)(n - 128) * stride)
                                      : (W0 + (size_t)n * stride);
  const float4* s4 = reinterpret_cast<const float4*>(src + g * 8);
  float4 lo = s4[0], hi = s4[1];
  bf16x8 b;
  b[0]=(__bf16)lo.x; b[1]=(__bf16)lo.y; b[2]=(__bf16)lo.z; b[3]=(__bf16)lo.w;
  b[4]=(__bf16)hi.x; b[5]=(__bf16)hi.y; b[6]=(__bf16)hi.z; b[7]=(__bf16)hi.w;
  reinterpret_cast<bf16x8*>(out)[idx] = b;
}

// one kernel: cq + 3 B-repacks + edge counting
__global__ __launch_bounds__(256) void prep_kernel(
    const float* __restrict__ Wq, const float* __restrict__ bq, const float* __restrict__ tb,
    const float* __restrict__ Wk, const float* __restrict__ Wv, const float* __restrict__ Wout,
    const int* __restrict__ dsti,
    float* __restrict__ cq, __bf16* __restrict__ Bq_kv, __bf16* __restrict__ Bq_q,
    __bf16* __restrict__ Bq_out, int* __restrict__ counts) {
  int b = blockIdx.x, tid = threadIdx.x;
  if (b == 0) {
    if (tid < 128) {
      float s = bq[tid];
      for (int j = 0; j < 128; ++j) s += cosf(tb[j]) * Wq[tid * 256 + 128 + j];
      cq[tid] = s;
    }
    return;
  }
  b -= 1;
  if (b < 48) { pack_frag(Wk, Wv, 384, 256, b * 256 + tid, Bq_kv); return; }
  b -= 48;
  if (b < 8)  { pack_frag(Wq, nullptr, 256, 128, b * 256 + tid, Bq_q); return; }
  b -= 8;
  if (b < 16) { pack_frag(Wout, nullptr, 256, 128, b * 256 + tid, Bq_out); return; }
  b -= 16;
  int e = b * 256 + tid;
  if (e < E_NUM) atomicAdd(&counts[dsti[e]], 1);
}

__global__ __launch_bounds__(1024) void scan_kernel(const int* __restrict__ counts,
    int* __restrict__ offs, int* __restrict__ cursor) {
  __shared__ int wpart[16];
  int tid = threadIdx.x, lane = tid & 63, wid = tid >> 6;
  int carry = 0;
  for (int base = 0; base < N_DST; base += 1024) {
    int idx = base + tid;
    int x = (idx < N_DST) ? counts[idx] : 0;
    int incl = x;
#pragma unroll
    for (int o = 1; o < 64; o <<= 1) {
      int y = __shfl_up(incl, o);
      if (lane >= o) incl += y;
    }
    if (lane == 63) wpart[wid] = incl;
    __syncthreads();
    if (wid == 0) {
      int v = (lane < 16) ? wpart[lane] : 0;
      int s = v;
#pragma unroll
      for (int o = 1; o < 16; o <<= 1) {
        int y = __shfl_up(s, o);
        if (lane >= o) s += y;
      }
      if (lane < 16) wpart[lane] = s;
    }
    __syncthreads();
    int woff = (wid > 0) ? wpart[wid - 1] : 0;
    int tot = wpart[15];
    if (idx < N_DST) {
      int v = carry + woff + incl - x;
      offs[idx] = v;
      cursor[idx] = v;
    }
    carry += tot;
    __syncthreads();
  }
  if (tid == 0) offs[N_DST] = carry;
}

__global__ __launch_bounds__(256) void fill_kernel(const int* __restrict__ dsti,
    int* __restrict__ cursor, int* __restrict__ elist, int* __restrict__ dsts) {
  int e = blockIdx.x * 256 + threadIdx.x;
  if (e < E_NUM) {
    int d = dsti[e];
    int p = atomicAdd(&cursor[d], 1);
    elist[p] = e;
    dsts[p] = d;
  }
}

// ============ KV kernel: async global_load_lds staging, fp32 LDS subtiles ============
// [K|V] = kv_in @ [Wk|Wv]^T + b over sorted edges; score from acc regs; V -> global.
// 6 K-subtiles of 64 fp32 cols: {src0,src1,edge0,edge1,cos0,cos1}, double-buffered.
__global__ __launch_bounds__(256, 4) void kv_kernel(
    const float* __restrict__ node_h, const float* __restrict__ edge_f,
    const float* __restrict__ dtp, const float* __restrict__ tw, const float* __restrict__ tb,
    const __bf16* __restrict__ Bq,
    const float* __restrict__ bk, const float* __restrict__ bv,
    const int* __restrict__ elist, const int* __restrict__ dsts,
    const float* __restrict__ Qn,
    __bf16* __restrict__ Vout, float* __restrict__ score)
{
  __shared__ __align__(16) float Abuf[2][4096];   // [2][64 rows][64 cols] fp32, XOR-swizzled
  __shared__ int Elds[64];
  __shared__ int Dlds[64];
  __shared__ float dts[64];
  __shared__ float twl[128];
  __shared__ float tbl[128];

  const int tid = threadIdx.x;
  const int e0 = blockIdx.x * 64;
  const int lane = tid & 63;
  const int w = tid >> 6;
  const int lrow = lane & 15;
  const int lk = lane >> 4;
  const int aswz = (lrow & 7) << 4;

  if (tid < 64) {
    int e = elist[e0 + tid];
    Elds[tid] = e;
    Dlds[tid] = dsts[e0 + tid];
    dts[tid] = dtp[e];
  } else if (tid < 192) {
    int j = tid - 64;
    twl[j] = tw[j];
    tbl[j] = tb[j];
  }
  __syncthreads();

  // stage subtile t (t<2: src cols t*64; else edge cols (t-2)*64) into buf via async DMA.
  // wave w issues instrs g=w*4..w*4+3; instr g covers rows 4g..4g+3 (1 KB, lane l -> +16B).
  // swizzle via pre-swizzled per-lane SOURCE offset: boff = ((l&15)*16) ^ ((row&7)<<4).
  auto stage_mem = [&](int t, int bufi) {
    const float* base;
    int coloff;
    if (t < 2) { base = node_h + (size_t)N_DST * 128; coloff = t * 64; }
    else       { base = edge_f;                       coloff = (t - 2) * 64; }
#pragma unroll
    for (int i = 0; i < 4; ++i) {
      int g = w * 4 + i;
      int r = g * 4 + (lane >> 4);
      const float* src = base + (size_t)Elds[r] * 128 + coloff;
      int boff = ((lane & 15) << 4) ^ ((r & 7) << 4);
      gload_lds16((const char*)src + boff, &Abuf[bufi][g * 256]);
    }
  };
  // cos subtile t (cols (t-4)*64): VALU compute + swizzled f32x4 LDS writes
  auto stage_cos = [&](int t, float* buf) {
    int r = tid >> 2;
    int j0 = (tid & 3) << 4;
    float d = dts[r];
    int swz = (r & 7) << 4;
    char* rowb = (char*)(buf + r * 64);
#pragma unroll
    for (int q = 0; q < 4; ++q) {
      f32x4 vv;
#pragma unroll
      for (int jj = 0; jj < 4; ++jj) {
        int J = (t - 4) * 64 + j0 + q * 4 + jj;
        vv[jj] = fast_cos(d * twl[J] + tbl[J]);
      }
      *reinterpret_cast<f32x4*>(rowb + (((j0 << 2) + (q << 4)) ^ swz)) = vv;
    }
  };

  f32x4 acc[4][4];
#pragma unroll
  for (int mf = 0; mf < 4; ++mf)
#pragma unroll
    for (int nf = 0; nf < 4; ++nf)
      acc[mf][nf] = (f32x4){0.f, 0.f, 0.f, 0.f};

  const bf16x8* __restrict__ Bw = reinterpret_cast<const bf16x8*>(Bq) + (size_t)(w * 4) * 64 + lane;

  auto ktile = [&](const float* buf, int t) {
#pragma unroll
    for (int ks = 0; ks < 2; ++ks) {
      int K32 = t * 2 + ks;
      bf16x8 b[4];
#pragma unroll
      for (int nf = 0; nf < 4; ++nf)
        b[nf] = Bw[((size_t)K32 * 16 + nf) * 64];
      bf16x8 a[4];
#pragma unroll
      for (int mf = 0; mf < 4; ++mf) {
        const char* rowb = (const char*)(buf + (mf * 16 + lrow) * 64);
        int cb = ks * 128 + lk * 32;
        f32x4 f0 = *reinterpret_cast<const f32x4*>(rowb + (cb ^ aswz));
        f32x4 f1 = *reinterpret_cast<const f32x4*>(rowb + ((cb + 16) ^ aswz));
        bf16x8 av;
#pragma unroll
        for (int j = 0; j < 4; ++j) {
          av[j] = (__bf16)f0[j];
          av[4 + j] = (__bf16)f1[j];
        }
        a[mf] = av;
      }
#pragma unroll
      for (int nf = 0; nf < 4; ++nf)
#pragma unroll
        for (int mf = 0; mf < 4; ++mf)
          acc[mf][nf] = __builtin_amdgcn_mfma_f32_16x16x32_bf16(a[mf], b[nf], acc[mf][nf], 0, 0, 0);
    }
  };

  stage_mem(0, 0);
  __syncthreads();                 // prologue: only exposed gather wait
#pragma unroll
  for (int t = 0; t < 6; ++t) {
    if (t < 3) stage_mem(t + 1, (t + 1) & 1);        // async DMA into other buffer
    else if (t < 5) stage_cos(t + 1, Abuf[(t + 1) & 1]);
    ktile(Abuf[t & 1], t);                           // compute current subtile
    __syncthreads();                                 // drains t+1 loads/writes
  }

  // ---- epilogue: scores from registers (waves 0,1), V via LDS bounce (waves 2,3)
  char* Vlds = (char*)Abuf[0];     // 64 rows x 256 B (bf16), swizzled
  if (w >= 2) {
#pragma unroll
    for (int nf = 0; nf < 4; ++nf) {
      int vcol = (w - 2) * 64 + nf * 16 + lrow;
      float bb = bv[vcol];
#pragma unroll
      for (int mf = 0; mf < 4; ++mf) {
#pragma unroll
        for (int r = 0; r < 4; ++r) {
          int row = mf * 16 + lk * 4 + r;
          *reinterpret_cast<__bf16*>(Vlds + row * 256 + ((vcol * 2) ^ ((row & 7) << 4))) =
              (__bf16)(acc[mf][nf][r] + bb);
        }
      }
    }
  } else {
    float bkv[4];
#pragma unroll
    for (int nf = 0; nf < 4; ++nf) bkv[nf] = bk[w * 64 + nf * 16 + lrow];
#pragma unroll
    for (int mf = 0; mf < 4; ++mf) {
#pragma unroll
      for (int r = 0; r < 4; ++r) {
        int row = mf * 16 + lk * 4 + r;
        const float* qrow = Qn + ((size_t)Dlds[row] << 7) + w * 64;
        float s = 0.f;
#pragma unroll
        for (int nf = 0; nf < 4; ++nf)
          s += (acc[mf][nf][r] + bkv[nf]) * qrow[nf * 16 + lrow];
        s += __shfl_xor(s, 1);
        s += __shfl_xor(s, 2);
        s += __shfl_xor(s, 4);
        s += __shfl_xor(s, 8);
        if (lrow == 0) {
          s = (s >= 0.f) ? s : 0.2f * s;
          score[((size_t)(e0 + row) << 1) + w] = s;
        }
      }
    }
  }
  __syncthreads();
#pragma unroll
  for (int i = 0; i < 4; ++i) {
    int c = tid + i * 256;
    int r = c >> 4, cb = (c & 15) << 4;
    bf16x8 vv = *reinterpret_cast<const bf16x8*>(Vlds + r * 256 + (cb ^ ((r & 7) << 4)));
    *reinterpret_cast<bf16x8*>(Vout + (((size_t)(e0 + r)) << 7) + (c & 15) * 8) = vv;
  }
}

// ---------------- MFMA GEMM (modes 0, 2), bf16 LDS staging ----------------
// MODE 0: Qn = tgt @ Wq1^T + cq                 (K=128)
// MODE 2: out = LN(relu([h|tgt] @ Wout^T+bout)) (K=256; dtp=gamma, tw=beta)
template<int MODE>
__global__ __launch_bounds__(256, 4) void gemm_kernel(
    const float* __restrict__ A0, const float* __restrict__ A1,
    const float* __restrict__ dtp, const float* __restrict__ tw,
    const __bf16* __restrict__ Bq, const float* __restrict__ bias0,
    float* __restrict__ outF)
{
  constexpr int NC = 128;
  constexpr int NFRAGW = 2;
  __shared__ __align__(16) char Abuf[2][64 * 256];

  const int tid = threadIdx.x;
  const int e0 = blockIdx.x * 64;
  const int nv = min(64, N_DST - e0);
  const int srow = tid >> 5;
  const int sc4 = (tid & 31) << 2;

  const int lane = tid & 63;
  const int w = tid >> 6;
  const int nbase = w * (NC / 4);
  const int lrow = lane & 15;
  const int lk = lane >> 4;
  const int aswz = (lrow & 7) << 4;
  const bf16x8* __restrict__ Bw =
      reinterpret_cast<const bf16x8*>(Bq) + (size_t)(w * NFRAGW) * 64 + lane;

  f32x4 acc[4][NFRAGW];
#pragma unroll
  for (int mf = 0; mf < 4; ++mf)
#pragma unroll
    for (int nf = 0; nf < NFRAGW; ++nf)
      acc[mf][nf] = (f32x4){0.f, 0.f, 0.f, 0.f};

  auto issueA = [&](int t, float4 (&v)[8]) {
    const float* base = (t == 0) ? A0 : A1;
#pragma unroll
    for (int i = 0; i < 8; ++i) {
      int r = srow + i * 8;
      v[i] = (r < nv) ? *reinterpret_cast<const float4*>(base + (size_t)(e0 + r) * 128 + sc4)
                      : make_float4(0.f, 0.f, 0.f, 0.f);
    }
  };
  auto writeA = [&](char* buf, float4 (&v)[8]) {
#pragma unroll
    for (int i = 0; i < 8; ++i) {
      int r = srow + i * 8;
      bf16x4 b;
      b[0]=(__bf16)v[i].x; b[1]=(__bf16)v[i].y; b[2]=(__bf16)v[i].z; b[3]=(__bf16)v[i].w;
      *reinterpret_cast<bf16x4*>(buf + r * 256 + ((sc4 * 2) ^ ((r & 7) << 4))) = b;
    }
  };
  auto ktile = [&](const char* buf, int t) {
#pragma unroll
    for (int ks = 0; ks < 4; ++ks) {
      bf16x8 b[NFRAGW];
#pragma unroll
      for (int nf = 0; nf < NFRAGW; ++nf)
        b[nf] = Bw[((size_t)(t * 4 + ks) * 4 * NFRAGW + nf) * 64];
      bf16x8 a[4];
#pragma unroll
      for (int mf = 0; mf < 4; ++mf)
        a[mf] = *reinterpret_cast<const bf16x8*>(
            buf + (mf * 16 + lrow) * 256 + (((ks * 32 + lk * 8) * 2) ^ aswz));
#pragma unroll
      for (int nf = 0; nf < NFRAGW; ++nf)
#pragma unroll
        for (int mf = 0; mf < 4; ++mf)
          acc[mf][nf] = __builtin_amdgcn_mfma_f32_16x16x32_bf16(a[mf], b[nf], acc[mf][nf], 0, 0, 0);
    }
  };

  float4 v[8];
  issueA(0, v);
  writeA(Abuf[0], v);
  __syncthreads();
  if constexpr (MODE == 2) {
    issueA(1, v);
    ktile(Abuf[0], 0);
    writeA(Abuf[1], v);
    __syncthreads();
    ktile(Abuf[1], 1);
  } else {
    ktile(Abuf[0], 0);
  }

  if constexpr (MODE == 0) {
#pragma unroll
    for (int nf = 0; nf < NFRAGW; ++nf) {
      int col = nbase + nf * 16 + lrow;
      float bb = bias0[col];
#pragma unroll
      for (int mf = 0; mf < 4; ++mf) {
#pragma unroll
        for (int r = 0; r < 4; ++r) {
          int row = mf * 16 + lk * 4 + r;
          if (row < nv)
            outF[(size_t)(e0 + row) * 128 + col] = acc[mf][nf][r] + bb;
        }
      }
    }
  } else {
    // fused relu + layernorm epilogue
    const float* gammaP = dtp;
    const float* betaP = tw;
    float vals[NFRAGW][4][4];
#pragma unroll
    for (int nf = 0; nf < NFRAGW; ++nf) {
      float bb = bias0[nbase + nf * 16 + lrow];
#pragma unroll
      for (int mf = 0; mf < 4; ++mf)
#pragma unroll
        for (int r = 0; r < 4; ++r)
          vals[nf][mf][r] = fmaxf(acc[mf][nf][r] + bb, 0.f);
    }
    __syncthreads();
    float* sums = reinterpret_cast<float*>(Abuf[0]);
    float* sqs  = reinterpret_cast<float*>(Abuf[0]) + 256;
    float* stats = reinterpret_cast<float*>(Abuf[0]) + 512;
#pragma unroll
    for (int mf = 0; mf < 4; ++mf) {
#pragma unroll
      for (int r = 0; r < 4; ++r) {
        float s1 = vals[0][mf][r] + vals[1][mf][r];
        float s2 = vals[0][mf][r] * vals[0][mf][r] + vals[1][mf][r] * vals[1][mf][r];
#pragma unroll
        for (int o = 1; o < 16; o <<= 1) {
          s1 += __shfl_xor(s1, o);
          s2 += __shfl_xor(s2, o);
        }
        if (lrow == 0) {
          int row = mf * 16 + lk * 4 + r;
          sums[w * 64 + row] = s1;
          sqs[w * 64 + row] = s2;
        }
      }
    }
    __syncthreads();
    if (tid < 64) {
      float s = sums[tid] + sums[64 + tid] + sums[128 + tid] + sums[192 + tid];
      float q = sqs[tid] + sqs[64 + tid] + sqs[128 + tid] + sqs[192 + tid];
      float mean = s * (1.f / 128.f);
      float var = q * (1.f / 128.f) - mean * mean;
      stats[tid * 2] = mean;
      stats[tid * 2 + 1] = rsqrtf(var + 1e-5f);
    }
    __syncthreads();
#pragma unroll
    for (int nf = 0; nf < NFRAGW; ++nf) {
      int col = nbase + nf * 16 + lrow;
      float g = gammaP[col], bC = betaP[col];
#pragma unroll
      for (int mf = 0; mf < 4; ++mf) {
#pragma unroll
        for (int r = 0; r < 4; ++r) {
          int row = mf * 16 + lk * 4 + r;
          if (row < nv) {
            float mean = stats[row * 2], rs = stats[row * 2 + 1];
            outF[(size_t)(e0 + row) * 128 + col] = (vals[nf][mf][r] - mean) * rs * g + bC;
          }
        }
      }
    }
  }
}

// ---------------- per-dst softmax + weighted V (sorted, streaming; 4 dst/block) ----------------
__global__ __launch_bounds__(256) void agg_kernel(const int* __restrict__ offs,
    const float* __restrict__ score, const __bf16* __restrict__ V, float* __restrict__ h) {
  int d = blockIdx.x * 4 + (threadIdx.x >> 6);
  if (d >= N_DST) return;
  int lane = threadIdx.x & 63;
  int beg = offs[d], end = offs[d + 1];
  int n = end - beg;
  float m0 = -3.0e38f, m1 = -3.0e38f;
  for (int i = lane; i < n; i += 64) {
    float2 sc = *reinterpret_cast<const float2*>(score + 2 * (size_t)(beg + i));
    m0 = fmaxf(m0, sc.x); m1 = fmaxf(m1, sc.y);
  }
#pragma unroll
  for (int o = 32; o; o >>= 1) {
    m0 = fmaxf(m0, __shfl_xor(m0, o));
    m1 = fmaxf(m1, __shfl_xor(m1, o));
  }
  float s0 = 0.f, s1 = 0.f;
  for (int i = lane; i < n; i += 64) {
    float2 sc = *reinterpret_cast<const float2*>(score + 2 * (size_t)(beg + i));
    s0 += __expf(sc.x - m0); s1 += __expf(sc.y - m1);
  }
#pragma unroll
  for (int o = 32; o; o >>= 1) {
    s0 += __shfl_xor(s0, o);
    s1 += __shfl_xor(s1, o);
  }
  float inv0 = (n > 0) ? 1.f / s0 : 0.f;
  float inv1 = (n > 0) ? 1.f / s1 : 0.f;
  int q = lane >> 4, j = lane & 15;
  int hsel = j >> 3;
  float acc[8];
#pragma unroll
  for (int k2 = 0; k2 < 8; ++k2) acc[k2] = 0.f;
  for (int i0 = 0; i0 < n; i0 += 4) {
    int i = i0 + q;
    if (i < n) {
      size_t p = beg + i;
      float2 sc = *reinterpret_cast<const float2*>(score + 2 * p);
      float wgt = hsel ? __expf(sc.y - m1) * inv1 : __expf(sc.x - m0) * inv0;
      bf16x8 v = *reinterpret_cast<const bf16x8*>(V + (p << 7) + j * 8);
#pragma unroll
      for (int k2 = 0; k2 < 8; ++k2) acc[k2] += wgt * (float)v[k2];
    }
  }
#pragma unroll
  for (int k2 = 0; k2 < 8; ++k2) {
    acc[k2] += __shfl_xor(acc[k2], 16);
    acc[k2] += __shfl_xor(acc[k2], 32);
  }
  if (q == 0) {
    float4 lo = make_float4(acc[0], acc[1], acc[2], acc[3]);
    float4 hi = make_float4(acc[4], acc[5], acc[6], acc[7]);
    float* dst = h + ((size_t)d << 7) + j * 8;
    *reinterpret_cast<float4*>(dst) = lo;
    *reinterpret_cast<float4*>(dst + 4) = hi;
  }
}

extern "C" void kernel_launch(void* const* d_in, const int* in_sizes, int n_in,
                              void* d_out, int out_size, void* d_ws, size_t ws_size,
                              hipStream_t stream) {
  (void)in_sizes; (void)n_in; (void)out_size; (void)ws_size;
  const float* node_h = (const float*)d_in[0];
  const float* edge_f = (const float*)d_in[1];
  const float* dtp    = (const float*)d_in[2];
  const int*   dsti   = (const int*)d_in[3];
  const float* tw     = (const float*)d_in[4];
  const float* tb     = (const float*)d_in[5];
  const float* Wq     = (const float*)d_in[6];
  const float* bq     = (const float*)d_in[7];
  const float* Wk     = (const float*)d_in[8];
  const float* bk     = (const float*)d_in[9];
  const float* Wv     = (const float*)d_in[10];
  const float* bv     = (const float*)d_in[11];
  const float* Wout   = (const float*)d_in[12];
  const float* bout   = (const float*)d_in[13];
  const float* gamma  = (const float*)d_in[14];
  const float* beta   = (const float*)d_in[15];
  float* outp = (float*)d_out;

  size_t off = 0;
  auto take = [&](size_t nbytes) -> void* {
    void* r = (char*)d_ws + off;
    off += (nbytes + 255) & ~(size_t)255;
    return r;
  };
  __bf16* Bq_kv  = (__bf16*)take((size_t)12288 * 16);
  __bf16* Bq_q   = (__bf16*)take((size_t)2048 * 16);
  __bf16* Bq_out = (__bf16*)take((size_t)4096 * 16);
  float*  cq     = (float*)take(128 * 4);
  float*  Qn     = (float*)take((size_t)N_DST * 128 * 4);
  __bf16* Vbuf   = (__bf16*)take((size_t)E_NUM * 128 * 2);
  float*  score  = (float*)take((size_t)E_NUM * 2 * 4);
  int*    counts = (int*)take((size_t)N_DST * 4);
  int*    offs   = (int*)take((size_t)(N_DST + 1) * 4);
  int*    cursor = (int*)take((size_t)N_DST * 4);
  int*    elist  = (int*)take((size_t)E_NUM * 4);
  int*    dsts   = (int*)take((size_t)E_NUM * 4);
  float*  hbuf   = (float*)take((size_t)N_DST * 128 * 4);

  hipMemsetAsync(counts, 0, (size_t)N_DST * 4, stream);

  const int count_blocks = (E_NUM + 255) / 256;
  prep_kernel<<<1 + 48 + 8 + 16 + count_blocks, 256, 0, stream>>>(
      Wq, bq, tb, Wk, Wv, Wout, dsti, cq, Bq_kv, Bq_q, Bq_out, counts);

  gemm_kernel<0><<<(N_DST + 63) / 64, 256, 0, stream>>>(node_h, nullptr, nullptr, nullptr,
      Bq_q, cq, Qn);

  scan_kernel<<<1, 1024, 0, stream>>>(counts, offs, cursor);
  fill_kernel<<<count_blocks, 256, 0, stream>>>(dsti, cursor, elist, dsts);

  kv_kernel<<<E_NUM / 64, 256, 0, stream>>>(node_h, edge_f, dtp, tw, tb,
      Bq_kv, bk, bv, elist, dsts, Qn, Vbuf, score);

  agg_kernel<<<(N_DST + 3) / 4, 256, 0, stream>>>(offs, score, Vbuf, hbuf);

  gemm_kernel<2><<<(N_DST + 63) / 64, 256, 0, stream>>>(hbuf, node_h, gamma, beta,
      Bq_out, bout, outp);
}

// Round 6
// 360.223 us; speedup vs baseline: 1.0127x; 1.0127x over previous
//
#include <hip/hip_runtime.h>

#define N_DST 25000
#define E_NUM 400000

typedef __bf16 bf16x8 __attribute__((ext_vector_type(8)));
typedef __bf16 bf16x4 __attribute__((ext_vector_type(4)));
typedef __bf16 bf16x2 __attribute__((ext_vector_type(2)));
typedef float  f32x4  __attribute__((ext_vector_type(4)));

__device__ __forceinline__ float fast_cos(float x) {
  float r = x * 0.15915494309189535f;
  r = r - floorf(r);
  return __builtin_amdgcn_cosf(r);
}

__device__ __forceinline__ void gload_lds16(const void* g, void* l) {
  __builtin_amdgcn_global_load_lds(
      (const __attribute__((address_space(1))) unsigned int*)g,
      (__attribute__((address_space(3))) unsigned int*)l, 16, 0, 0);
}

// pinned waitcnt + barrier (sched_barrier sandwich keeps loads from crossing)
#define PIPE_WAIT(S)                         \
  do {                                       \
    __builtin_amdgcn_sched_barrier(0);       \
    asm volatile(S ::: "memory");            \
    __builtin_amdgcn_sched_barrier(0);       \
    __builtin_amdgcn_s_barrier();            \
    __builtin_amdgcn_sched_barrier(0);       \
  } while (0)

// pack W into frag-contiguous bf16: out[fid*64+lane] = W[n][g*8..g*8+7]
__device__ __forceinline__ void pack_frag(const float* __restrict__ W0,
    const float* __restrict__ W1, int stride, int NC, int idx, __bf16* __restrict__ out) {
  int lane = idx & 63, fid = idx >> 6;
  int nfw = NC >> 6;
  int perks = nfw << 2;
  int ks = fid / perks, rem = fid - ks * perks;
  int w = rem / nfw, nf = rem - w * nfw;
  int n = w * (NC >> 2) + nf * 16 + (lane & 15);
  int g = (ks << 2) + (lane >> 4);
  const float* src = (W1 && n >= 128) ? (W1 + (size_t)(n - 128) * stride)
                                      : (W0 + (size_t)n * stride);
  const float4* s4 = reinterpret_cast<const float4*>(src + g * 8);
  float4 lo = s4[0], hi = s4[1];
  bf16x8 b;
  b[0]=(__bf16)lo.x; b[1]=(__bf16)lo.y; b[2]=(__bf16)lo.z; b[3]=(__bf16)lo.w;
  b[4]=(__bf16)hi.x; b[5]=(__bf16)hi.y; b[6]=(__bf16)hi.z; b[7]=(__bf16)hi.w;
  reinterpret_cast<bf16x8*>(out)[idx] = b;
}

// one kernel: cq + 3 B-repacks + edge counting
__global__ __launch_bounds__(256) void prep_kernel(
    const float* __restrict__ Wq, const float* __restrict__ bq, const float* __restrict__ tb,
    const float* __restrict__ Wk, const float* __restrict__ Wv, const float* __restrict__ Wout,
    const int* __restrict__ dsti,
    float* __restrict__ cq, __bf16* __restrict__ Bq_kv, __bf16* __restrict__ Bq_q,
    __bf16* __restrict__ Bq_out, int* __restrict__ counts) {
  int b = blockIdx.x, tid = threadIdx.x;
  if (b == 0) {
    if (tid < 128) {
      float s = bq[tid];
      for (int j = 0; j < 128; ++j) s += cosf(tb[j]) * Wq[tid * 256 + 128 + j];
      cq[tid] = s;
    }
    return;
  }
  b -= 1;
  if (b < 48) { pack_frag(Wk, Wv, 384, 256, b * 256 + tid, Bq_kv); return; }
  b -= 48;
  if (b < 8)  { pack_frag(Wq, nullptr, 256, 128, b * 256 + tid, Bq_q); return; }
  b -= 8;
  if (b < 16) { pack_frag(Wout, nullptr, 256, 128, b * 256 + tid, Bq_out); return; }
  b -= 16;
  int e = b * 256 + tid;
  if (e < E_NUM) atomicAdd(&counts[dsti[e]], 1);
}

__global__ __launch_bounds__(1024) void scan_kernel(const int* __restrict__ counts,
    int* __restrict__ offs, int* __restrict__ cursor) {
  __shared__ int wpart[16];
  int tid = threadIdx.x, lane = tid & 63, wid = tid >> 6;
  int carry = 0;
  for (int base = 0; base < N_DST; base += 1024) {
    int idx = base + tid;
    int x = (idx < N_DST) ? counts[idx] : 0;
    int incl = x;
#pragma unroll
    for (int o = 1; o < 64; o <<= 1) {
      int y = __shfl_up(incl, o);
      if (lane >= o) incl += y;
    }
    if (lane == 63) wpart[wid] = incl;
    __syncthreads();
    if (wid == 0) {
      int v = (lane < 16) ? wpart[lane] : 0;
      int s = v;
#pragma unroll
      for (int o = 1; o < 16; o <<= 1) {
        int y = __shfl_up(s, o);
        if (lane >= o) s += y;
      }
      if (lane < 16) wpart[lane] = s;
    }
    __syncthreads();
    int woff = (wid > 0) ? wpart[wid - 1] : 0;
    int tot = wpart[15];
    if (idx < N_DST) {
      int v = carry + woff + incl - x;
      offs[idx] = v;
      cursor[idx] = v;
    }
    carry += tot;
    __syncthreads();
  }
  if (tid == 0) offs[N_DST] = carry;
}

// pos[e] = sorted position of edge e
__global__ __launch_bounds__(256) void fill_kernel(const int* __restrict__ dsti,
    int* __restrict__ cursor, int* __restrict__ pos) {
  int e = blockIdx.x * 256 + threadIdx.x;
  if (e < E_NUM) {
    int d = dsti[e];
    int p = atomicAdd(&cursor[d], 1);
    pos[e] = p;
  }
}

// ============ KV kernel: NATURAL edge order, sequential DMA, counted-vmcnt pipeline ============
// [K|V] = kv_in @ [Wk|Wv]^T + b; score from acc regs (Q gathered from L3);
// V rows + scores scatter-written to dst-sorted positions via pos[].
// 6 K-subtiles of 64 fp32 cols {src0,src1,edge0,edge1,cos0,cos1}, 3-buffer rotation.
__global__ __launch_bounds__(256, 3) void kv_kernel(
    const float* __restrict__ node_h, const float* __restrict__ edge_f,
    const float* __restrict__ dtp, const float* __restrict__ tw, const float* __restrict__ tb,
    const __bf16* __restrict__ Bq,
    const float* __restrict__ bk, const float* __restrict__ bv,
    const int* __restrict__ dsti, const int* __restrict__ pos,
    const float* __restrict__ Qn,
    __bf16* __restrict__ Vout, float* __restrict__ score)
{
  __shared__ __align__(16) float Abuf[3][4096];   // [3][64 rows][64 cols] fp32, XOR-swizzled
  __shared__ int Dlds[64];
  __shared__ int Plds[64];
  __shared__ float dts[64];
  __shared__ float twl[128];
  __shared__ float tbl[128];

  const int tid = threadIdx.x;
  const int e0 = blockIdx.x * 64;
  const int lane = tid & 63;
  const int w = tid >> 6;
  const int lrow = lane & 15;
  const int lk = lane >> 4;
  const int aswz = (lrow & 7) << 4;

  if (tid < 64) {
    Dlds[tid] = dsti[e0 + tid];
    Plds[tid] = pos[e0 + tid];
    dts[tid] = dtp[e0 + tid];
  } else if (tid < 192) {
    int j = tid - 64;
    twl[j] = tw[j];
    tbl[j] = tb[j];
  }
  __syncthreads();   // clean slate: vmcnt/lgkm drained, tables published

  // stage subtile t: t<2 -> src cols t*64; t<4 -> edge cols (t-2)*64. Sequential rows!
  // instr g covers tile rows 4g..4g+3; per-lane source pre-swizzled (XOR bit4),
  // LDS dest linear (wave-uniform base + lane*16).
  auto stage_mem = [&](int t, int bufi) {
    const char* base;
    if (t < 2) base = (const char*)(node_h + ((size_t)(N_DST + e0)) * 128 + t * 64);
    else       base = (const char*)(edge_f + (size_t)e0 * 128 + (t - 2) * 64);
#pragma unroll
    for (int i = 0; i < 4; ++i) {
      int g = w * 4 + i;
      int r = g * 4 + (lane >> 4);
      int srcoff = r * 512 + ((((lane & 15) << 4)) ^ ((r & 7) << 4));
      gload_lds16(base + srcoff, &Abuf[bufi][g * 256]);
    }
  };
  // cos subtile t (cols (t-4)*64): VALU compute + swizzled f32x4 LDS writes
  auto stage_cos = [&](int t, float* buf) {
    int r = tid >> 2;
    int j0 = (tid & 3) << 4;
    float d = dts[r];
    int swz = (r & 7) << 4;
    char* rowb = (char*)(buf + r * 64);
#pragma unroll
    for (int q = 0; q < 4; ++q) {
      f32x4 vv;
#pragma unroll
      for (int jj = 0; jj < 4; ++jj) {
        int J = (t - 4) * 64 + j0 + q * 4 + jj;
        vv[jj] = fast_cos(d * twl[J] + tbl[J]);
      }
      *reinterpret_cast<f32x4*>(rowb + (((j0 << 2) + (q << 4)) ^ swz)) = vv;
    }
  };

  f32x4 acc[4][4];
#pragma unroll
  for (int mf = 0; mf < 4; ++mf)
#pragma unroll
    for (int nf = 0; nf < 4; ++nf)
      acc[mf][nf] = (f32x4){0.f, 0.f, 0.f, 0.f};

  const bf16x8* __restrict__ Bw = reinterpret_cast<const bf16x8*>(Bq) + (size_t)(w * 4) * 64 + lane;

  auto ktile = [&](const float* buf, int t) {
#pragma unroll
    for (int ks = 0; ks < 2; ++ks) {
      int K32 = t * 2 + ks;
      bf16x8 b[4];
#pragma unroll
      for (int nf = 0; nf < 4; ++nf)
        b[nf] = Bw[((size_t)K32 * 16 + nf) * 64];
      bf16x8 a[4];
#pragma unroll
      for (int mf = 0; mf < 4; ++mf) {
        const char* rowb = (const char*)(buf + (mf * 16 + lrow) * 64);
        int cb = ks * 128 + lk * 32;
        f32x4 f0 = *reinterpret_cast<const f32x4*>(rowb + (cb ^ aswz));
        f32x4 f1 = *reinterpret_cast<const f32x4*>(rowb + ((cb + 16) ^ aswz));
        bf16x8 av;
#pragma unroll
        for (int j = 0; j < 4; ++j) {
          av[j] = (__bf16)f0[j];
          av[4 + j] = (__bf16)f1[j];
        }
        a[mf] = av;
      }
#pragma unroll
      for (int nf = 0; nf < 4; ++nf)
#pragma unroll
        for (int mf = 0; mf < 4; ++mf)
          acc[mf][nf] = __builtin_amdgcn_mfma_f32_16x16x32_bf16(a[mf], b[nf], acc[mf][nf], 0, 0, 0);
    }
  };

  // ---- counted-vmcnt pipeline (per-wave: 4 DMA per stage) ----
  stage_mem(0, 0);
  stage_mem(1, 1);
  PIPE_WAIT("s_waitcnt vmcnt(4)");                 // b0 ready; stage1 in flight
  stage_mem(2, 2); ktile(Abuf[0], 0);
  PIPE_WAIT("s_waitcnt vmcnt(4)");                 // b1 ready; stage2 in flight
  stage_mem(3, 0); ktile(Abuf[1], 1);              // b0 free (read in phase0)
  PIPE_WAIT("s_waitcnt vmcnt(4)");                 // b2 ready; stage3 in flight
  stage_cos(4, Abuf[1]); ktile(Abuf[2], 2);        // b1 free (read in phase1)
  PIPE_WAIT("s_waitcnt vmcnt(0) lgkmcnt(0)");      // b0(stage3) ready; cos4 published
  stage_cos(5, Abuf[2]); ktile(Abuf[0], 3);        // b2 free (read in phase2)
  PIPE_WAIT("s_waitcnt lgkmcnt(0)");               // cos5 published
  ktile(Abuf[1], 4);                               // no LDS writes -> no barriers
  ktile(Abuf[2], 5);

  // ---- epilogue: scores from regs (waves 0,1; Q gathered from L2/L3),
  //      V via LDS bounce (waves 2,3), then scatter-store to sorted rows.
  char* Vlds = (char*)Abuf[0];
  if (w >= 2) {
#pragma unroll
    for (int nf = 0; nf < 4; ++nf) {
      int vcol = (w - 2) * 64 + nf * 16 + lrow;
      float bb = bv[vcol];
#pragma unroll
      for (int mf = 0; mf < 4; ++mf) {
#pragma unroll
        for (int r = 0; r < 4; ++r) {
          int row = mf * 16 + lk * 4 + r;
          *reinterpret_cast<__bf16*>(Vlds + row * 256 + ((vcol * 2) ^ ((row & 7) << 4))) =
              (__bf16)(acc[mf][nf][r] + bb);
        }
      }
    }
  } else {
    float bkv[4];
#pragma unroll
    for (int nf = 0; nf < 4; ++nf) bkv[nf] = bk[w * 64 + nf * 16 + lrow];
#pragma unroll
    for (int mf = 0; mf < 4; ++mf) {
#pragma unroll
      for (int r = 0; r < 4; ++r) {
        int row = mf * 16 + lk * 4 + r;
        const float* qrow = Qn + ((size_t)Dlds[row] << 7) + w * 64;
        float s = 0.f;
#pragma unroll
        for (int nf = 0; nf < 4; ++nf)
          s += (acc[mf][nf][r] + bkv[nf]) * qrow[nf * 16 + lrow];
        s += __shfl_xor(s, 1);
        s += __shfl_xor(s, 2);
        s += __shfl_xor(s, 4);
        s += __shfl_xor(s, 8);
        if (lrow == 0) {
          s = (s >= 0.f) ? s : 0.2f * s;
          score[((size_t)Plds[row] << 1) + w] = s;
        }
      }
    }
  }
  __syncthreads();
#pragma unroll
  for (int i = 0; i < 4; ++i) {
    int c = tid + i * 256;
    int r = c >> 4, cb = (c & 15) << 4;
    bf16x8 vv = *reinterpret_cast<const bf16x8*>(Vlds + r * 256 + (cb ^ ((r & 7) << 4)));
    *reinterpret_cast<bf16x8*>(Vout + (((size_t)Plds[r]) << 7) + (c & 15) * 8) = vv;
  }
}

// ---------------- MFMA GEMM (modes 0, 2), bf16 LDS staging ----------------
// MODE 0: Qn = tgt @ Wq1^T + cq                 (K=128)
// MODE 2: out = LN(relu([h|tgt] @ Wout^T+bout)) (K=256; dtp=gamma, tw=beta)
template<int MODE>
__global__ __launch_bounds__(256, 4) void gemm_kernel(
    const float* __restrict__ A0, const float* __restrict__ A1,
    const float* __restrict__ dtp, const float* __restrict__ tw,
    const __bf16* __restrict__ Bq, const float* __restrict__ bias0,
    float* __restrict__ outF)
{
  constexpr int NC = 128;
  constexpr int NFRAGW = 2;
  __shared__ __align__(16) char Abuf[2][64 * 256];

  const int tid = threadIdx.x;
  const int e0 = blockIdx.x * 64;
  const int nv = min(64, N_DST - e0);
  const int srow = tid >> 5;
  const int sc4 = (tid & 31) << 2;

  const int lane = tid & 63;
  const int w = tid >> 6;
  const int nbase = w * (NC / 4);
  const int lrow = lane & 15;
  const int lk = lane >> 4;
  const int aswz = (lrow & 7) << 4;
  const bf16x8* __restrict__ Bw =
      reinterpret_cast<const bf16x8*>(Bq) + (size_t)(w * NFRAGW) * 64 + lane;

  f32x4 acc[4][NFRAGW];
#pragma unroll
  for (int mf = 0; mf < 4; ++mf)
#pragma unroll
    for (int nf = 0; nf < NFRAGW; ++nf)
      acc[mf][nf] = (f32x4){0.f, 0.f, 0.f, 0.f};

  auto issueA = [&](int t, float4 (&v)[8]) {
    const float* base = (t == 0) ? A0 : A1;
#pragma unroll
    for (int i = 0; i < 8; ++i) {
      int r = srow + i * 8;
      v[i] = (r < nv) ? *reinterpret_cast<const float4*>(base + (size_t)(e0 + r) * 128 + sc4)
                      : make_float4(0.f, 0.f, 0.f, 0.f);
    }
  };
  auto writeA = [&](char* buf, float4 (&v)[8]) {
#pragma unroll
    for (int i = 0; i < 8; ++i) {
      int r = srow + i * 8;
      bf16x4 b;
      b[0]=(__bf16)v[i].x; b[1]=(__bf16)v[i].y; b[2]=(__bf16)v[i].z; b[3]=(__bf16)v[i].w;
      *reinterpret_cast<bf16x4*>(buf + r * 256 + ((sc4 * 2) ^ ((r & 7) << 4))) = b;
    }
  };
  auto ktile = [&](const char* buf, int t) {
#pragma unroll
    for (int ks = 0; ks < 4; ++ks) {
      bf16x8 b[NFRAGW];
#pragma unroll
      for (int nf = 0; nf < NFRAGW; ++nf)
        b[nf] = Bw[((size_t)(t * 4 + ks) * 4 * NFRAGW + nf) * 64];
      bf16x8 a[4];
#pragma unroll
      for (int mf = 0; mf < 4; ++mf)
        a[mf] = *reinterpret_cast<const bf16x8*>(
            buf + (mf * 16 + lrow) * 256 + (((ks * 32 + lk * 8) * 2) ^ aswz));
#pragma unroll
      for (int nf = 0; nf < NFRAGW; ++nf)
#pragma unroll
        for (int mf = 0; mf < 4; ++mf)
          acc[mf][nf] = __builtin_amdgcn_mfma_f32_16x16x32_bf16(a[mf], b[nf], acc[mf][nf], 0, 0, 0);
    }
  };

  float4 v[8];
  issueA(0, v);
  writeA(Abuf[0], v);
  __syncthreads();
  if constexpr (MODE == 2) {
    issueA(1, v);
    ktile(Abuf[0], 0);
    writeA(Abuf[1], v);
    __syncthreads();
    ktile(Abuf[1], 1);
  } else {
    ktile(Abuf[0], 0);
  }

  if constexpr (MODE == 0) {
#pragma unroll
    for (int nf = 0; nf < NFRAGW; ++nf) {
      int col = nbase + nf * 16 + lrow;
      float bb = bias0[col];
#pragma unroll
      for (int mf = 0; mf < 4; ++mf) {
#pragma unroll
        for (int r = 0; r < 4; ++r) {
          int row = mf * 16 + lk * 4 + r;
          if (row < nv)
            outF[(size_t)(e0 + row) * 128 + col] = acc[mf][nf][r] + bb;
        }
      }
    }
  } else {
    // fused relu + layernorm epilogue
    const float* gammaP = dtp;
    const float* betaP = tw;
    float vals[NFRAGW][4][4];
#pragma unroll
    for (int nf = 0; nf < NFRAGW; ++nf) {
      float bb = bias0[nbase + nf * 16 + lrow];
#pragma unroll
      for (int mf = 0; mf < 4; ++mf)
#pragma unroll
        for (int r = 0; r < 4; ++r)
          vals[nf][mf][r] = fmaxf(acc[mf][nf][r] + bb, 0.f);
    }
    __syncthreads();
    float* sums = reinterpret_cast<float*>(Abuf[0]);
    float* sqs  = reinterpret_cast<float*>(Abuf[0]) + 256;
    float* stats = reinterpret_cast<float*>(Abuf[0]) + 512;
#pragma unroll
    for (int mf = 0; mf < 4; ++mf) {
#pragma unroll
      for (int r = 0; r < 4; ++r) {
        float s1 = vals[0][mf][r] + vals[1][mf][r];
        float s2 = vals[0][mf][r] * vals[0][mf][r] + vals[1][mf][r] * vals[1][mf][r];
#pragma unroll
        for (int o = 1; o < 16; o <<= 1) {
          s1 += __shfl_xor(s1, o);
          s2 += __shfl_xor(s2, o);
        }
        if (lrow == 0) {
          int row = mf * 16 + lk * 4 + r;
          sums[w * 64 + row] = s1;
          sqs[w * 64 + row] = s2;
        }
      }
    }
    __syncthreads();
    if (tid < 64) {
      float s = sums[tid] + sums[64 + tid] + sums[128 + tid] + sums[192 + tid];
      float q = sqs[tid] + sqs[64 + tid] + sqs[128 + tid] + sqs[192 + tid];
      float mean = s * (1.f / 128.f);
      float var = q * (1.f / 128.f) - mean * mean;
      stats[tid * 2] = mean;
      stats[tid * 2 + 1] = rsqrtf(var + 1e-5f);
    }
    __syncthreads();
#pragma unroll
    for (int nf = 0; nf < NFRAGW; ++nf) {
      int col = nbase + nf * 16 + lrow;
      float g = gammaP[col], bC = betaP[col];
#pragma unroll
      for (int mf = 0; mf < 4; ++mf) {
#pragma unroll
        for (int r = 0; r < 4; ++r) {
          int row = mf * 16 + lk * 4 + r;
          if (row < nv) {
            float mean = stats[row * 2], rs = stats[row * 2 + 1];
            outF[(size_t)(e0 + row) * 128 + col] = (vals[nf][mf][r] - mean) * rs * g + bC;
          }
        }
      }
    }
  }
}

// ---------------- per-dst softmax + weighted V (all sequential; 4 dst/block) ----------------
__global__ __launch_bounds__(256) void agg_kernel(const int* __restrict__ offs,
    const float* __restrict__ score, const __bf16* __restrict__ V, float* __restrict__ h) {
  int d = blockIdx.x * 4 + (threadIdx.x >> 6);
  if (d >= N_DST) return;
  int lane = threadIdx.x & 63;
  int beg = offs[d], end = offs[d + 1];
  int n = end - beg;
  float m0 = -3.0e38f, m1 = -3.0e38f;
  for (int i = lane; i < n; i += 64) {
    float2 sc = *reinterpret_cast<const float2*>(score + 2 * (size_t)(beg + i));
    m0 = fmaxf(m0, sc.x); m1 = fmaxf(m1, sc.y);
  }
#pragma unroll
  for (int o = 32; o; o >>= 1) {
    m0 = fmaxf(m0, __shfl_xor(m0, o));
    m1 = fmaxf(m1, __shfl_xor(m1, o));
  }
  float s0 = 0.f, s1 = 0.f;
  for (int i = lane; i < n; i += 64) {
    float2 sc = *reinterpret_cast<const float2*>(score + 2 * (size_t)(beg + i));
    s0 += __expf(sc.x - m0); s1 += __expf(sc.y - m1);
  }
#pragma unroll
  for (int o = 32; o; o >>= 1) {
    s0 += __shfl_xor(s0, o);
    s1 += __shfl_xor(s1, o);
  }
  float inv0 = (n > 0) ? 1.f / s0 : 0.f;
  float inv1 = (n > 0) ? 1.f / s1 : 0.f;
  int q = lane >> 4, j = lane & 15;
  int hsel = j >> 3;
  float acc[8];
#pragma unroll
  for (int k2 = 0; k2 < 8; ++k2) acc[k2] = 0.f;
  for (int i0 = 0; i0 < n; i0 += 4) {
    int i = i0 + q;
    if (i < n) {
      size_t p = beg + i;
      float2 sc = *reinterpret_cast<const float2*>(score + 2 * p);
      float wgt = hsel ? __expf(sc.y - m1) * inv1 : __expf(sc.x - m0) * inv0;
      bf16x8 v = *reinterpret_cast<const bf16x8*>(V + (p << 7) + j * 8);
#pragma unroll
      for (int k2 = 0; k2 < 8; ++k2) acc[k2] += wgt * (float)v[k2];
    }
  }
#pragma unroll
  for (int k2 = 0; k2 < 8; ++k2) {
    acc[k2] += __shfl_xor(acc[k2], 16);
    acc[k2] += __shfl_xor(acc[k2], 32);
  }
  if (q == 0) {
    float4 lo = make_float4(acc[0], acc[1], acc[2], acc[3]);
    float4 hi = make_float4(acc[4], acc[5], acc[6], acc[7]);
    float* dst = h + ((size_t)d << 7) + j * 8;
    *reinterpret_cast<float4*>(dst) = lo;
    *reinterpret_cast<float4*>(dst + 4) = hi;
  }
}

extern "C" void kernel_launch(void* const* d_in, const int* in_sizes, int n_in,
                              void* d_out, int out_size, void* d_ws, size_t ws_size,
                              hipStream_t stream) {
  (void)in_sizes; (void)n_in; (void)out_size; (void)ws_size;
  const float* node_h = (const float*)d_in[0];
  const float* edge_f = (const float*)d_in[1];
  const float* dtp    = (const float*)d_in[2];
  const int*   dsti   = (const int*)d_in[3];
  const float* tw     = (const float*)d_in[4];
  const float* tb     = (const float*)d_in[5];
  const float* Wq     = (const float*)d_in[6];
  const float* bq     = (const float*)d_in[7];
  const float* Wk     = (const float*)d_in[8];
  const float* bk     = (const float*)d_in[9];
  const float* Wv     = (const float*)d_in[10];
  const float* bv     = (const float*)d_in[11];
  const float* Wout   = (const float*)d_in[12];
  const float* bout   = (const float*)d_in[13];
  const float* gamma  = (const float*)d_in[14];
  const float* beta   = (const float*)d_in[15];
  float* outp = (float*)d_out;

  size_t off = 0;
  auto take = [&](size_t nbytes) -> void* {
    void* r = (char*)d_ws + off;
    off += (nbytes + 255) & ~(size_t)255;
    return r;
  };
  __bf16* Bq_kv  = (__bf16*)take((size_t)12288 * 16);
  __bf16* Bq_q   = (__bf16*)take((size_t)2048 * 16);
  __bf16* Bq_out = (__bf16*)take((size_t)4096 * 16);
  float*  cq     = (float*)take(128 * 4);
  float*  Qn     = (float*)take((size_t)N_DST * 128 * 4);
  __bf16* Vbuf   = (__bf16*)take((size_t)E_NUM * 128 * 2);
  float*  score  = (float*)take((size_t)E_NUM * 2 * 4);
  int*    counts = (int*)take((size_t)N_DST * 4);
  int*    offs   = (int*)take((size_t)(N_DST + 1) * 4);
  int*    cursor = (int*)take((size_t)N_DST * 4);
  int*    pos    = (int*)take((size_t)E_NUM * 4);
  float*  hbuf   = (float*)take((size_t)N_DST * 128 * 4);

  hipMemsetAsync(counts, 0, (size_t)N_DST * 4, stream);

  const int count_blocks = (E_NUM + 255) / 256;
  prep_kernel<<<1 + 48 + 8 + 16 + count_blocks, 256, 0, stream>>>(
      Wq, bq, tb, Wk, Wv, Wout, dsti, cq, Bq_kv, Bq_q, Bq_out, counts);

  gemm_kernel<0><<<(N_DST + 63) / 64, 256, 0, stream>>>(node_h, nullptr, nullptr, nullptr,
      Bq_q, cq, Qn);

  scan_kernel<<<1, 1024, 0, stream>>>(counts, offs, cursor);
  fill_kernel<<<count_blocks, 256, 0, stream>>>(dsti, cursor, pos);

  kv_kernel<<<E_NUM / 64, 256, 0, stream>>>(node_h, edge_f, dtp, tw, tb,
      Bq_kv, bk, bv, dsti, pos, Qn, Vbuf, score);

  agg_kernel<<<(N_DST + 3) / 4, 256, 0, stream>>>(offs, score, Vbuf, hbuf);

  gemm_kernel<2><<<(N_DST + 63) / 64, 256, 0, stream>>>(hbuf, node_h, gamma, beta,
      Bq_out, bout, outp);
}